// Round 14
// baseline (540.845 us; speedup 1.0000x reference)
//
#include <hip/hip_runtime.h>

#define MDIM 8192   // B*S
#define KDIM 4096   // DIN
#define NDIM 11008  // DOUT

#define NBLK_W 1024

typedef float f32x4 __attribute__((ext_vector_type(4)));
typedef int   i32x4 __attribute__((ext_vector_type(4)));
typedef char  c4    __attribute__((ext_vector_type(4)));

#define GAS __attribute__((address_space(1)))
#define LAS __attribute__((address_space(3)))

// --- Kernel 1: sign(W) -> {-1,0,+1} i8, fused with |W| partial reduction ---
__global__ __launch_bounds__(256) void k_convert_w(const float* __restrict__ w,
                                                   char* __restrict__ wq,
                                                   float* __restrict__ partials) {
  const int n4 = (NDIM * KDIM) / 4;
  const int stride = gridDim.x * blockDim.x;
  float s = 0.f;
  for (int i = blockIdx.x * blockDim.x + threadIdx.x; i < n4; i += stride) {
    f32x4 v = ((const f32x4*)w)[i];
    s += fabsf(v.x) + fabsf(v.y) + fabsf(v.z) + fabsf(v.w);
    c4 q;
    q.x = v.x > 0.f ? 1 : (v.x < 0.f ? -1 : 0);
    q.y = v.y > 0.f ? 1 : (v.y < 0.f ? -1 : 0);
    q.z = v.z > 0.f ? 1 : (v.z < 0.f ? -1 : 0);
    q.w = v.w > 0.f ? 1 : (v.w < 0.f ? -1 : 0);
    ((c4*)wq)[i] = q;
  }
  #pragma unroll
  for (int off = 32; off > 0; off >>= 1) s += __shfl_down(s, off, 64);
  __shared__ float red[4];
  if ((threadIdx.x & 63) == 0) red[threadIdx.x >> 6] = s;
  __syncthreads();
  if (threadIdx.x == 0) partials[blockIdx.x] = red[0] + red[1] + red[2] + red[3];
}

// --- Kernel 2: deterministic final reduction -> scale_w = mean|W| ---
__global__ __launch_bounds__(256) void k_scale(const float* __restrict__ partials,
                                               float* __restrict__ scale) {
  float s = 0.f;
  for (int i = threadIdx.x; i < NBLK_W; i += 256) s += partials[i];
  #pragma unroll
  for (int off = 32; off > 0; off >>= 1) s += __shfl_down(s, off, 64);
  __shared__ float red[4];
  if ((threadIdx.x & 63) == 0) red[threadIdx.x >> 6] = s;
  __syncthreads();
  if (threadIdx.x == 0)
    *scale = (red[0] + red[1] + red[2] + red[3]) / (float)((size_t)NDIM * KDIM);
}

// --- Kernel 3: x fp32 -> i8 with per-row scale s_x[m] = max|x[m,:]|/127 ---
__global__ __launch_bounds__(256) void k_convert_x(const float* __restrict__ x,
                                                   char* __restrict__ xq,
                                                   float* __restrict__ sx) {
  const int row = blockIdx.x;
  const float* xr = x + (size_t)row * KDIM;
  const int t = (int)threadIdx.x;
  f32x4 v[4];
  float mx = 0.f;
  #pragma unroll
  for (int j = 0; j < 4; ++j) {
    v[j] = *(const f32x4*)(xr + j * 1024 + t * 4);
    mx = fmaxf(mx, fmaxf(fmaxf(fabsf(v[j].x), fabsf(v[j].y)),
                         fmaxf(fabsf(v[j].z), fabsf(v[j].w))));
  }
  #pragma unroll
  for (int off = 32; off > 0; off >>= 1) mx = fmaxf(mx, __shfl_xor(mx, off, 64));
  __shared__ float red[4];
  __shared__ float bmax;
  if ((t & 63) == 0) red[t >> 6] = mx;
  __syncthreads();
  if (t == 0) {
    float m2 = fmaxf(fmaxf(red[0], red[1]), fmaxf(red[2], red[3]));
    m2 = fmaxf(m2, 1e-20f);
    bmax = m2;
    sx[row] = m2 * (1.f / 127.f);
  }
  __syncthreads();
  const float r = 127.f / bmax;
  #pragma unroll
  for (int j = 0; j < 4; ++j) {
    int a = __float2int_rn(v[j].x * r), b = __float2int_rn(v[j].y * r);
    int c = __float2int_rn(v[j].z * r), d = __float2int_rn(v[j].w * r);
    a = a > 127 ? 127 : (a < -127 ? -127 : a);
    b = b > 127 ? 127 : (b < -127 ? -127 : b);
    c = c > 127 ? 127 : (c < -127 ? -127 : c);
    d = d > 127 ? 127 : (d < -127 ? -127 : d);
    c4 q; q.x = (char)a; q.y = (char)b; q.z = (char)c; q.w = (char)d;
    *(c4*)(xq + (size_t)row * KDIM + j * 1024 + t * 4) = q;
  }
}

// --- Kernel 4: 128x256 8-phase i8 MFMA GEMM, 2 blocks/CU ---
// C[m][n] = scale_w * sx[m] * (sum_k xq[m][k]*wq[n][k]) + bias[n]
// CHANGE vs r13 (256x256, 1 block/CU, 766 cyc/phase vs 455 work = ~310 cyc
// latency/phase unhidden): halve BM -> per-wave 64x64, acc 64 AGPR, frags 24
// VGPR -> fits __launch_bounds__(512,4) = 2 BLOCKS/CU. Desynchronized blocks
// fill each other's barrier/VM/lgkm bubbles (m114: pipes co-schedule across
// waves). Bonus: nwg 1376->2752, tail loss 11.6%->2.3%.
// 8 waves (2M x 4N), per-wave 64x64 = 4x4 16-tiles; 4 MFMA(16x16x64 i8)/phase,
// 2 K-tiles/iter (buf0=K2i, buf1=K2i+1), 8 phases/iter, MFMA-first 1-bar/phase.
// LDS 48 KiB: buf0{A:0(8K), B:8192(16K,h0/h1)} buf1{A:24576, B:32768}.
// Stage = ONE 8KB global_load_lds op (512 x 16B, 128 rows x 64B).
// Quadrant order (r13-mirror): (L,01)(L,23)(H,01)(H,23); af[2] reused L/H.
// Load map (1 ahead): pre:afL(b0),bq01(b0); g0:bq23(b0); g1:afH(b0);
//   g3:afL(b1)+bq01(b1); g4:bq23(b1); g5:afH(b1); g7:afL(b0')+bq01(b0').
// Stage slots: g0: b1.B.h0<-kA; g1: b1.B.h1<-kA; g3: b0.A<-kB; g4: b0.B.h0<-kB;
//   g5: b0.B.h1<-kB; g7: b1.A<-kC (next iter's kA; WAR: b1.A readers consumed g6).
// VM(0) at g2/g6-end, before BAR: g2 drains {prev-g7, g0, g1} = buf1 complete
//   before g3's post-BAR reads; g6 drains {g3,g4,g5} = buf0 complete before g7.
//   VM(0)-only => spill-SAFE (over-drains); the stall hides under the other block.
// WAR ledger (checked): b0.A@g3 readers consumed g2 (1-phase, r13 distance);
//   b0.B@g4/g5 readers consumed g1/g3 (reads complete before first consumer);
//   b1.B@g0/g1 readers consumed prev-g5/g7; b1.A@g7 readers consumed g6.
// Frag layout + 3-bit swizzle identical to r13 (correctness-verified there).

#define BAR()  __builtin_amdgcn_s_barrier()
#define SB0()  __builtin_amdgcn_sched_barrier(0)
#define PRIO1() __builtin_amdgcn_s_setprio(1)
#define PRIO0() __builtin_amdgcn_s_setprio(0)
#define VM(N)  asm volatile("s_waitcnt vmcnt(" #N ")" ::: "memory")

// One 8KB half-tile: 128 rows x 64 B; GROWB = global row base of the 128 rows
#define STAGE(GP, GROWB, LDSBASE, KT) do {                                            \
  const char* _s = (GP) + (size_t)((GROWB) + srow) * KDIM + (KT)*64 + scol;           \
  char* _d = lds + (LDSBASE) + tid*16;                                                \
  __builtin_amdgcn_global_load_lds((const GAS unsigned int*)_s,                       \
                                   (LAS unsigned int*)_d, 16, 0, 0);                  \
} while (0)

// B frag pair: DST[ni] covers output cols wn*64 + NH*32 + ni*16 + l15
#define LOAD_B2(DST, BUF, NH)                                                         \
  _Pragma("unroll") for (int ni = 0; ni < 2; ++ni)                                    \
    DST[ni] = *(const i32x4*)&lds[(BUF)*24576 + 8192 + bWOff + (NH)*2048 + ni*1024    \
                                  + rowoff + rcol];

// A frag pair: DST[mi] covers output rows wm*64 + MH*32 + mi*16 + l15
#define LOAD_A2(DST, BUF, MH)                                                         \
  _Pragma("unroll") for (int mi = 0; mi < 2; ++mi)                                    \
    DST[mi] = *(const i32x4*)&lds[(BUF)*24576 + aWOff + (MH)*2048 + mi*1024           \
                                  + rowoff + rcol];

// 4 MFMA (16x16x64 i8): 2 mi x 2 ni -> acc[MB+mi][NB+ni]
#define MFMA4(AF, MB, BQ, NB)                                                         \
  _Pragma("unroll") for (int mi = 0; mi < 2; ++mi)                                    \
  _Pragma("unroll") for (int ni = 0; ni < 2; ++ni)                                    \
    acc[(MB)+mi][(NB)+ni] = __builtin_amdgcn_mfma_i32_16x16x64_i8(                    \
        AF[mi], BQ[ni], acc[(MB)+mi][(NB)+ni], 0, 0, 0);

__global__ __launch_bounds__(512, 4) void k_gemm256(const char* __restrict__ A,
                                                    const char* __restrict__ B,
                                                    const float* __restrict__ bias,
                                                    const float* __restrict__ sx,
                                                    const float* __restrict__ scale_p,
                                                    float* __restrict__ C) {
  extern __shared__ char lds[];

  const int nTn = NDIM / 256;                  // 43
  const int nwg = (MDIM / 128) * nTn;          // 2752 (== 0 mod 8)
  int wg = (int)blockIdx.x;
  wg = (wg & 7) * (nwg / 8) + (wg >> 3);       // XCD-aware swizzle (bijective)
  const int tm = wg / nTn;                     // 0..63
  const int tn = wg % nTn;                     // 0..42

  const int tid  = (int)threadIdx.x;
  const int lane = tid & 63;
  const int wave = tid >> 6;                   // 0..7
  const int wm   = wave >> 2;                  // 0..1  (M)
  const int wn   = wave & 3;                   // 0..3  (N)
  const int l15  = lane & 15;

  // read-side (r13-verified): row = l15 (+16-mults), byte col swizzled
  const int rowoff = l15 * 64;
  const int rcol = ((lane >> 4) << 4) ^ (((l15 >> 1) & 3) << 4);
  // stage-side (r13-verified): linear LDS dest; pre-swizzled global source col
  const int srow = tid >> 2;                   // 0..127
  const int scol = ((tid & 3) << 4) ^ (((tid >> 3) & 3) << 4);

  const int aWOff = wm * 4096;                 // this wave's 64 A-rows (bytes)
  const int bWOff = wn * 4096;                 // this wave's 64 B-rows (bytes)
  const int aRow = tm * 128;
  const int bRow = tn * 256;

  i32x4 acc[4][4];
  #pragma unroll
  for (int i = 0; i < 4; ++i)
    #pragma unroll
    for (int j = 0; j < 4; ++j) acc[i][j] = i32x4{0, 0, 0, 0};

  i32x4 af[2], bq01[2], bq23[2];

  // ---- prologue: buf0{A,B.h0,B.h1}<-K0; buf1.A<-K1; drain; preload g0 ----
  STAGE(A, aRow,        0,     0);
  STAGE(B, bRow,        8192,  0);
  STAGE(B, bRow + 128,  16384, 0);
  STAGE(A, aRow,        24576, 1);
  VM(0);
  SB0();
  BAR();
  LOAD_A2(af, 0, 0); LOAD_B2(bq01, 0, 0);      // operands for g0

  #pragma unroll 1
  for (int i = 0; i < 32; ++i) {
    const int kA = 2 * i + 1;                            // <= 63
    const int kB = (2 * i + 2 > 63) ? 63 : 2 * i + 2;    // clamped tail
    const int kC = (2 * i + 3 > 63) ? 63 : 2 * i + 3;
    // g0: MFMA(afL,bq01)@b0; load bq23(b0); stage b1.B.h0 <- kA
    PRIO1(); MFMA4(af, 0, bq01, 0); PRIO0(); SB0();
    LOAD_B2(bq23, 0, 1);
    STAGE(B, bRow,       32768, kA);
    BAR();
    // g1: MFMA(afL,bq23); load afH(b0) (WAR-pinned after MFMA); stage b1.B.h1
    PRIO1(); MFMA4(af, 0, bq23, 2); PRIO0(); SB0();
    LOAD_A2(af, 0, 1);
    STAGE(B, bRow + 128, 40960, kA);
    BAR();
    // g2: MFMA(afH,bq01); no loads/stage; VM(0) -> buf1 fully landed
    PRIO1(); MFMA4(af, 2, bq01, 0); PRIO0(); SB0();
    VM(0); SB0();
    BAR();
    // g3: MFMA(afH,bq23); load afL(b1)+bq01(b1); stage b0.A <- kB
    PRIO1(); MFMA4(af, 2, bq23, 2); PRIO0(); SB0();
    LOAD_A2(af, 1, 0); LOAD_B2(bq01, 1, 0);
    STAGE(A, aRow,       0,     kB);
    BAR();
    // g4: MFMA(afL,bq01)@b1; load bq23(b1); stage b0.B.h0 <- kB
    PRIO1(); MFMA4(af, 0, bq01, 0); PRIO0(); SB0();
    LOAD_B2(bq23, 1, 1);
    STAGE(B, bRow,       8192,  kB);
    BAR();
    // g5: MFMA(afL,bq23); load afH(b1); stage b0.B.h1 <- kB
    PRIO1(); MFMA4(af, 0, bq23, 2); PRIO0(); SB0();
    LOAD_A2(af, 1, 1);
    STAGE(B, bRow + 128, 16384, kB);
    BAR();
    // g6: MFMA(afH,bq01); no loads/stage; VM(0) -> buf0 fully landed
    PRIO1(); MFMA4(af, 2, bq01, 0); PRIO0(); SB0();
    VM(0); SB0();
    BAR();
    // g7: MFMA(afH,bq23); load afL(b0')+bq01(b0'); stage b1.A <- kC (next kA)
    PRIO1(); MFMA4(af, 2, bq23, 2); PRIO0(); SB0();
    LOAD_A2(af, 0, 0); LOAD_B2(bq01, 0, 0);
    STAGE(A, aRow,       24576, kC);
    BAR();
  }

  VM(0);  // drain the final g7 stage before epilogue

  const float sc = *scale_p;
  float bv[4];
  #pragma unroll
  for (int ni = 0; ni < 4; ++ni) bv[ni] = bias[tn * 256 + wn * 64 + ni * 16 + l15];

  // C/D layout (dtype-independent): col = lane&15, row = (lane>>4)*4 + reg
  #pragma unroll
  for (int mi = 0; mi < 4; ++mi) {
    #pragma unroll
    for (int r = 0; r < 4; ++r) {
      const int m = tm * 128 + wm * 64 + mi * 16 + (lane >> 4) * 4 + r;
      const float srow_scale = sc * sx[m];
      float* crow = C + (size_t)m * NDIM + tn * 256 + wn * 64;
      #pragma unroll
      for (int ni = 0; ni < 4; ++ni)
        crow[ni * 16 + l15] = srow_scale * (float)acc[mi][ni][r] + bv[ni];
    }
  }
}

extern "C" void kernel_launch(void* const* d_in, const int* in_sizes, int n_in,
                              void* d_out, int out_size, void* d_ws, size_t ws_size,
                              hipStream_t stream) {
  const float* x = (const float*)d_in[0];
  const float* w = (const float*)d_in[1];
  const float* bias = (const float*)d_in[2];
  float* out = (float*)d_out;

  char* ws = (char*)d_ws;
  const size_t XQ_BYTES = (size_t)MDIM * KDIM;   // 33,554,432
  const size_t WQ_BYTES = (size_t)NDIM * KDIM;   // 45,088,768
  char* xq = ws;
  char* wq = ws + XQ_BYTES;
  float* sx = (float*)(ws + XQ_BYTES + WQ_BYTES);
  float* partials = sx + MDIM;
  float* scale = partials + NBLK_W;

  k_convert_w<<<NBLK_W, 256, 0, stream>>>(w, wq, partials);
  k_scale<<<1, 256, 0, stream>>>(partials, scale);
  k_convert_x<<<MDIM, 256, 0, stream>>>(x, xq, sx);

  (void)hipFuncSetAttribute((const void*)k_gemm256,
                            hipFuncAttributeMaxDynamicSharedMemorySize, 49152);
  const int grid = (MDIM / 128) * (NDIM / 256);  // 2752
  k_gemm256<<<grid, 512, 49152, stream>>>(xq, wq, bias, sx, scale, out);
}

// Round 15
// 517.732 us; speedup vs baseline: 1.0446x; 1.0446x over previous
//
#include <hip/hip_runtime.h>

#define MDIM 8192   // B*S
#define KDIM 4096   // DIN
#define NDIM 11008  // DOUT

#define NBLK_W 1024

typedef float f32x4 __attribute__((ext_vector_type(4)));
typedef int   i32x4 __attribute__((ext_vector_type(4)));
typedef char  c4    __attribute__((ext_vector_type(4)));

#define GAS __attribute__((address_space(1)))
#define LAS __attribute__((address_space(3)))

// --- Kernel 1: sign(W) -> {-1,0,+1} i8, fused with |W| partial reduction ---
__global__ __launch_bounds__(256) void k_convert_w(const float* __restrict__ w,
                                                   char* __restrict__ wq,
                                                   float* __restrict__ partials) {
  const int n4 = (NDIM * KDIM) / 4;
  const int stride = gridDim.x * blockDim.x;
  float s = 0.f;
  for (int i = blockIdx.x * blockDim.x + threadIdx.x; i < n4; i += stride) {
    f32x4 v = ((const f32x4*)w)[i];
    s += fabsf(v.x) + fabsf(v.y) + fabsf(v.z) + fabsf(v.w);
    c4 q;
    q.x = v.x > 0.f ? 1 : (v.x < 0.f ? -1 : 0);
    q.y = v.y > 0.f ? 1 : (v.y < 0.f ? -1 : 0);
    q.z = v.z > 0.f ? 1 : (v.z < 0.f ? -1 : 0);
    q.w = v.w > 0.f ? 1 : (v.w < 0.f ? -1 : 0);
    ((c4*)wq)[i] = q;
  }
  #pragma unroll
  for (int off = 32; off > 0; off >>= 1) s += __shfl_down(s, off, 64);
  __shared__ float red[4];
  if ((threadIdx.x & 63) == 0) red[threadIdx.x >> 6] = s;
  __syncthreads();
  if (threadIdx.x == 0) partials[blockIdx.x] = red[0] + red[1] + red[2] + red[3];
}

// --- Kernel 2: deterministic final reduction -> scale_w = mean|W| ---
__global__ __launch_bounds__(256) void k_scale(const float* __restrict__ partials,
                                               float* __restrict__ scale) {
  float s = 0.f;
  for (int i = threadIdx.x; i < NBLK_W; i += 256) s += partials[i];
  #pragma unroll
  for (int off = 32; off > 0; off >>= 1) s += __shfl_down(s, off, 64);
  __shared__ float red[4];
  if ((threadIdx.x & 63) == 0) red[threadIdx.x >> 6] = s;
  __syncthreads();
  if (threadIdx.x == 0)
    *scale = (red[0] + red[1] + red[2] + red[3]) / (float)((size_t)NDIM * KDIM);
}

// --- Kernel 3: x fp32 -> i8 with per-row scale s_x[m] = max|x[m,:]|/127 ---
__global__ __launch_bounds__(256) void k_convert_x(const float* __restrict__ x,
                                                   char* __restrict__ xq,
                                                   float* __restrict__ sx) {
  const int row = blockIdx.x;
  const float* xr = x + (size_t)row * KDIM;
  const int t = (int)threadIdx.x;
  f32x4 v[4];
  float mx = 0.f;
  #pragma unroll
  for (int j = 0; j < 4; ++j) {
    v[j] = *(const f32x4*)(xr + j * 1024 + t * 4);
    mx = fmaxf(mx, fmaxf(fmaxf(fabsf(v[j].x), fabsf(v[j].y)),
                         fmaxf(fabsf(v[j].z), fabsf(v[j].w))));
  }
  #pragma unroll
  for (int off = 32; off > 0; off >>= 1) mx = fmaxf(mx, __shfl_xor(mx, off, 64));
  __shared__ float red[4];
  __shared__ float bmax;
  if ((t & 63) == 0) red[t >> 6] = mx;
  __syncthreads();
  if (t == 0) {
    float m2 = fmaxf(fmaxf(red[0], red[1]), fmaxf(red[2], red[3]));
    m2 = fmaxf(m2, 1e-20f);
    bmax = m2;
    sx[row] = m2 * (1.f / 127.f);
  }
  __syncthreads();
  const float r = 127.f / bmax;
  #pragma unroll
  for (int j = 0; j < 4; ++j) {
    int a = __float2int_rn(v[j].x * r), b = __float2int_rn(v[j].y * r);
    int c = __float2int_rn(v[j].z * r), d = __float2int_rn(v[j].w * r);
    a = a > 127 ? 127 : (a < -127 ? -127 : a);
    b = b > 127 ? 127 : (b < -127 ? -127 : b);
    c = c > 127 ? 127 : (c < -127 ? -127 : c);
    d = d > 127 ? 127 : (d < -127 ? -127 : d);
    c4 q; q.x = (char)a; q.y = (char)b; q.z = (char)c; q.w = (char)d;
    *(c4*)(xq + (size_t)row * KDIM + j * 1024 + t * 4) = q;
  }
}

// --- Kernel 4: 128x256 8-phase i8 MFMA GEMM, 2 blocks/CU + 8x8 super-tiles ---
// C[m][n] = scale_w * sx[m] * (sum_k xq[m][k]*wq[n][k]) + bias[n]
// CHANGE vs r14 (462us GEMM, FETCH 1.38GB): grid ORDER only. r14's row-major
// order made the ~64 concurrent WGs/XCD span 1.5 rows x 43 cols -> B-panel
// fill ~64MB per 64 tiles. New 8x8 super-tile order: each XCD's chunk (344
// consecutive swizzled wgs = one 8-row band) walks 8tm x 8tn blocks -> fill
// per 64 tiles = 8 A-panels (4MB, ~L2-resident) + 8 B-panels (8MB, L3-stream)
// = 12MB (~5x less). Body identical to r14 (pass, absmax 0.03125).
// Mapping (bijective, verified): wg' = XCD-swizzle(wg); band = wg'/344 (0..7);
//   rem = wg'%344; tn = rem>>3 (0..42); tm = band*8 + (rem&7) (0..63).
// 8 waves (2M x 4N), per-wave 64x64; 4 MFMA(16x16x64 i8)/phase, 2 K-tiles/iter,
// 8 phases/iter, MFMA-first 1-bar/phase; LDS 48KB; VM(0)@g2/g6 (spill-safe).
// Stage slots: g0:b1.B.h0<-kA; g1:b1.B.h1<-kA; g3:b0.A<-kB; g4:b0.B.h0<-kB;
//   g5:b0.B.h1<-kB; g7:b1.A<-kC. Load map (1 ahead): pre:afL(b0),bq01(b0);
//   g0:bq23(b0); g1:afH(b0); g3:afL(b1)+bq01(b1); g4:bq23(b1); g5:afH(b1);
//   g7:afL(b0')+bq01(b0'). WAR/RAW ledger unchanged from r14 (verified there).
// Frag layout + 3-bit swizzle identical to r13/r14 (verified).

#define BAR()  __builtin_amdgcn_s_barrier()
#define SB0()  __builtin_amdgcn_sched_barrier(0)
#define PRIO1() __builtin_amdgcn_s_setprio(1)
#define PRIO0() __builtin_amdgcn_s_setprio(0)
#define VM(N)  asm volatile("s_waitcnt vmcnt(" #N ")" ::: "memory")

// One 8KB half-tile: 128 rows x 64 B; GROWB = global row base of the 128 rows
#define STAGE(GP, GROWB, LDSBASE, KT) do {                                            \
  const char* _s = (GP) + (size_t)((GROWB) + srow) * KDIM + (KT)*64 + scol;           \
  char* _d = lds + (LDSBASE) + tid*16;                                                \
  __builtin_amdgcn_global_load_lds((const GAS unsigned int*)_s,                       \
                                   (LAS unsigned int*)_d, 16, 0, 0);                  \
} while (0)

// B frag pair: DST[ni] covers output cols wn*64 + NH*32 + ni*16 + l15
#define LOAD_B2(DST, BUF, NH)                                                         \
  _Pragma("unroll") for (int ni = 0; ni < 2; ++ni)                                    \
    DST[ni] = *(const i32x4*)&lds[(BUF)*24576 + 8192 + bWOff + (NH)*2048 + ni*1024    \
                                  + rowoff + rcol];

// A frag pair: DST[mi] covers output rows wm*64 + MH*32 + mi*16 + l15
#define LOAD_A2(DST, BUF, MH)                                                         \
  _Pragma("unroll") for (int mi = 0; mi < 2; ++mi)                                    \
    DST[mi] = *(const i32x4*)&lds[(BUF)*24576 + aWOff + (MH)*2048 + mi*1024           \
                                  + rowoff + rcol];

// 4 MFMA (16x16x64 i8): 2 mi x 2 ni -> acc[MB+mi][NB+ni]
#define MFMA4(AF, MB, BQ, NB)                                                         \
  _Pragma("unroll") for (int mi = 0; mi < 2; ++mi)                                    \
  _Pragma("unroll") for (int ni = 0; ni < 2; ++ni)                                    \
    acc[(MB)+mi][(NB)+ni] = __builtin_amdgcn_mfma_i32_16x16x64_i8(                    \
        AF[mi], BQ[ni], acc[(MB)+mi][(NB)+ni], 0, 0, 0);

__global__ __launch_bounds__(512, 4) void k_gemm256(const char* __restrict__ A,
                                                    const char* __restrict__ B,
                                                    const float* __restrict__ bias,
                                                    const float* __restrict__ sx,
                                                    const float* __restrict__ scale_p,
                                                    float* __restrict__ C) {
  extern __shared__ char lds[];

  const int nTn = NDIM / 256;                  // 43
  const int nwg = (MDIM / 128) * nTn;          // 2752 (== 0 mod 8)
  int wg = (int)blockIdx.x;
  wg = (wg & 7) * (nwg / 8) + (wg >> 3);       // XCD-aware swizzle (bijective)
  // 8x8 super-tile order within each XCD band (L2 panel reuse):
  const int band = wg / (nTn * 8);             // 0..7
  const int rem  = wg % (nTn * 8);             // 0..343
  const int tn   = rem >> 3;                   // 0..42
  const int tm   = band * 8 + (rem & 7);       // 0..63

  const int tid  = (int)threadIdx.x;
  const int lane = tid & 63;
  const int wave = tid >> 6;                   // 0..7
  const int wm   = wave >> 2;                  // 0..1  (M)
  const int wn   = wave & 3;                   // 0..3  (N)
  const int l15  = lane & 15;

  // read-side (r13-verified): row = l15 (+16-mults), byte col swizzled
  const int rowoff = l15 * 64;
  const int rcol = ((lane >> 4) << 4) ^ (((l15 >> 1) & 3) << 4);
  // stage-side (r13-verified): linear LDS dest; pre-swizzled global source col
  const int srow = tid >> 2;                   // 0..127
  const int scol = ((tid & 3) << 4) ^ (((tid >> 3) & 3) << 4);

  const int aWOff = wm * 4096;                 // this wave's 64 A-rows (bytes)
  const int bWOff = wn * 4096;                 // this wave's 64 B-rows (bytes)
  const int aRow = tm * 128;
  const int bRow = tn * 256;

  i32x4 acc[4][4];
  #pragma unroll
  for (int i = 0; i < 4; ++i)
    #pragma unroll
    for (int j = 0; j < 4; ++j) acc[i][j] = i32x4{0, 0, 0, 0};

  i32x4 af[2], bq01[2], bq23[2];

  // ---- prologue: buf0{A,B.h0,B.h1}<-K0; buf1.A<-K1; drain; preload g0 ----
  STAGE(A, aRow,        0,     0);
  STAGE(B, bRow,        8192,  0);
  STAGE(B, bRow + 128,  16384, 0);
  STAGE(A, aRow,        24576, 1);
  VM(0);
  SB0();
  BAR();
  LOAD_A2(af, 0, 0); LOAD_B2(bq01, 0, 0);      // operands for g0

  #pragma unroll 1
  for (int i = 0; i < 32; ++i) {
    const int kA = 2 * i + 1;                            // <= 63
    const int kB = (2 * i + 2 > 63) ? 63 : 2 * i + 2;    // clamped tail
    const int kC = (2 * i + 3 > 63) ? 63 : 2 * i + 3;
    // g0: MFMA(afL,bq01)@b0; load bq23(b0); stage b1.B.h0 <- kA
    PRIO1(); MFMA4(af, 0, bq01, 0); PRIO0(); SB0();
    LOAD_B2(bq23, 0, 1);
    STAGE(B, bRow,       32768, kA);
    BAR();
    // g1: MFMA(afL,bq23); load afH(b0) (WAR-pinned after MFMA); stage b1.B.h1
    PRIO1(); MFMA4(af, 0, bq23, 2); PRIO0(); SB0();
    LOAD_A2(af, 0, 1);
    STAGE(B, bRow + 128, 40960, kA);
    BAR();
    // g2: MFMA(afH,bq01); no loads/stage; VM(0) -> buf1 fully landed
    PRIO1(); MFMA4(af, 2, bq01, 0); PRIO0(); SB0();
    VM(0); SB0();
    BAR();
    // g3: MFMA(afH,bq23); load afL(b1)+bq01(b1); stage b0.A <- kB
    PRIO1(); MFMA4(af, 2, bq23, 2); PRIO0(); SB0();
    LOAD_A2(af, 1, 0); LOAD_B2(bq01, 1, 0);
    STAGE(A, aRow,       0,     kB);
    BAR();
    // g4: MFMA(afL,bq01)@b1; load bq23(b1); stage b0.B.h0 <- kB
    PRIO1(); MFMA4(af, 0, bq01, 0); PRIO0(); SB0();
    LOAD_B2(bq23, 1, 1);
    STAGE(B, bRow,       8192,  kB);
    BAR();
    // g5: MFMA(afL,bq23); load afH(b1); stage b0.B.h1 <- kB
    PRIO1(); MFMA4(af, 0, bq23, 2); PRIO0(); SB0();
    LOAD_A2(af, 1, 1);
    STAGE(B, bRow + 128, 16384, kB);
    BAR();
    // g6: MFMA(afH,bq01); no loads/stage; VM(0) -> buf0 fully landed
    PRIO1(); MFMA4(af, 2, bq01, 0); PRIO0(); SB0();
    VM(0); SB0();
    BAR();
    // g7: MFMA(afH,bq23); load afL(b0')+bq01(b0'); stage b1.A <- kC (next kA)
    PRIO1(); MFMA4(af, 2, bq23, 2); PRIO0(); SB0();
    LOAD_A2(af, 0, 0); LOAD_B2(bq01, 0, 0);
    STAGE(A, aRow,       24576, kC);
    BAR();
  }

  VM(0);  // drain the final g7 stage before epilogue

  const float sc = *scale_p;
  float bv[4];
  #pragma unroll
  for (int ni = 0; ni < 4; ++ni) bv[ni] = bias[tn * 256 + wn * 64 + ni * 16 + l15];

  // C/D layout (dtype-independent): col = lane&15, row = (lane>>4)*4 + reg
  #pragma unroll
  for (int mi = 0; mi < 4; ++mi) {
    #pragma unroll
    for (int r = 0; r < 4; ++r) {
      const int m = tm * 128 + wm * 64 + mi * 16 + (lane >> 4) * 4 + r;
      const float srow_scale = sc * sx[m];
      float* crow = C + (size_t)m * NDIM + tn * 256 + wn * 64;
      #pragma unroll
      for (int ni = 0; ni < 4; ++ni)
        crow[ni * 16 + l15] = srow_scale * (float)acc[mi][ni][r] + bv[ni];
    }
  }
}

extern "C" void kernel_launch(void* const* d_in, const int* in_sizes, int n_in,
                              void* d_out, int out_size, void* d_ws, size_t ws_size,
                              hipStream_t stream) {
  const float* x = (const float*)d_in[0];
  const float* w = (const float*)d_in[1];
  const float* bias = (const float*)d_in[2];
  float* out = (float*)d_out;

  char* ws = (char*)d_ws;
  const size_t XQ_BYTES = (size_t)MDIM * KDIM;   // 33,554,432
  const size_t WQ_BYTES = (size_t)NDIM * KDIM;   // 45,088,768
  char* xq = ws;
  char* wq = ws + XQ_BYTES;
  float* sx = (float*)(ws + XQ_BYTES + WQ_BYTES);
  float* partials = sx + MDIM;
  float* scale = partials + NBLK_W;

  k_convert_w<<<NBLK_W, 256, 0, stream>>>(w, wq, partials);
  k_scale<<<1, 256, 0, stream>>>(partials, scale);
  k_convert_x<<<MDIM, 256, 0, stream>>>(x, xq, sx);

  (void)hipFuncSetAttribute((const void*)k_gemm256,
                            hipFuncAttributeMaxDynamicSharedMemorySize, 49152);
  const int grid = (MDIM / 128) * (NDIM / 256);  // 2752
  k_gemm256<<<grid, 512, 49152, stream>>>(xq, wq, bias, sx, scale, out);
}